// Round 5
// baseline (666.105 us; speedup 1.0000x reference)
//
#include <hip/hip_runtime.h>
#include <hip/hip_bf16.h>

typedef __attribute__((ext_vector_type(8))) short bf16x8;
typedef __attribute__((ext_vector_type(4))) float f32x4;

// ---------- helpers ----------
__device__ __forceinline__ unsigned short f2bf(float v) {
    union { __hip_bfloat16 h; unsigned short u; } cv;
    cv.h = __float2bfloat16(v);           // hw RNE convert
    return cv.u;
}
__device__ __forceinline__ float bf2f(unsigned short u) {
    return __uint_as_float(((unsigned int)u) << 16);
}
__device__ __forceinline__ float sigm(float x) { return 1.f / (1.f + __expf(-x)); }
__device__ __forceinline__ float tanh_(float x) { return 2.f / (1.f + __expf(-2.f * x)) - 1.f; }
__device__ __forceinline__ float adjW(int i, int j) {
    const float inv[8] = {1.f/4.f, 1.f/5.f, 1.f/6.f, 1.f/7.f,
                          1.f/7.f, 1.f/6.f, 1.f/5.f, 1.f/4.f};
    int d = i - j; d = d < 0 ? -d : d;
    return (d >= 1 && d <= 4) ? inv[i] : 0.f;
}

// =====================================================================
// K0: convert weights to bf16 into ws.
// layout (u16 elems): [0 Wl12 32768][32768 Wr12 32768][65536 wih 98304][163840 whh 98304]
// =====================================================================
__global__ __launch_bounds__(256) void k0_wconv(const float* __restrict__ Wl12,
    const float* __restrict__ Wr12, const float* __restrict__ wih,
    const float* __restrict__ whh, unsigned short* __restrict__ wbf)
{
    int i = blockIdx.x * 256 + threadIdx.x;   // 0..262143
    float v;
    if (i < 32768)       v = Wl12[i];
    else if (i < 65536)  v = Wr12[i - 32768];
    else if (i < 163840) v = wih[i - 65536];
    else                 v = whh[i - 163840];
    wbf[i] = f2bf(v);
}

// =====================================================================
// K1: fused graph stage. h in hT (bf16) with RMW residual epilogue.
// Weight staging: global_load_lds width-16 into LINEAR wlds[128*128] with
// XOR-swizzled source (byte ^= ((col&7)<<4)); reads apply same XOR.
// 512 thr (4 wr x 2 wc waves), 16 graphs/block.
// =====================================================================
__device__ __forceinline__ void stage_w(const unsigned short* mat,
                                        unsigned short* wlds, int t)
{
    #pragma unroll
    for (int i = 0; i < 4; ++i) {
        int O = (i * 512 + t) * 16;                       // linear byte offset
        int src = O ^ (((O >> 8) & 7) << 4);              // pre-swizzled source
        const void* g = (const char*)mat + src;
        void* lp = (char*)wlds + (i * 512 + (t & ~63)) * 16;  // wave-uniform base
        __builtin_amdgcn_global_load_lds(
            (const __attribute__((address_space(1))) void*)g,
            (__attribute__((address_space(3))) void*)lp, 16, 0, 0);
    }
}
__device__ __forceinline__ bf16x8 rdW(const unsigned short* wlds, int C, int kb)
{
    int off = (C << 8) + (kb << 1);
    off ^= (C & 7) << 4;
    return *(const bf16x8*)((const char*)wlds + off);
}

__global__ __launch_bounds__(512, 4) void k1_sage(
    const float* __restrict__ iq,
    const float* __restrict__ Wl0, const float* __restrict__ bl0, const float* __restrict__ Wr0,
    const unsigned short* __restrict__ wbf,
    const float* __restrict__ bl12,
    const float* __restrict__ lng, const float* __restrict__ lnb,
    float* __restrict__ pf)
{
    __shared__ unsigned short wlds[128 * 128];   // 32 KB, linear+swizzled
    __shared__ unsigned short hT[128][136];      // 34.8 KB h master (bf16)
    __shared__ float statS[128][4];
    __shared__ float xS[128][2], axS[128][2];

    const int t  = threadIdx.x;
    const int l  = t & 63;
    const int w  = t >> 6;
    const int wr = w >> 1, wc = w & 1;
    const int lc = l & 15, li = l >> 4;
    const int kgrp = li * 8;
    const int half = li & 1;
    const int g0 = blockIdx.x * 16;

    // ---- issue Wl(lay=1) staging early (async) ----
    stage_w(wbf, wlds, t);

    // ---- patchify ----
    if (t < 256) {
        int r = t >> 1, c = t & 1;
        int gid = g0 + (r >> 3);
        int node = r & 7;
        int b = gid / 31, p = gid - b * 31;
        xS[r][c] = iq[((size_t)b * 2 + c) * 128 + p * 4 + node];
    }
    __syncthreads();
    if (t < 256) {
        int r = t >> 1, c = t & 1;
        int node = r & 7, base = r & ~7;
        float s = 0.f;
        #pragma unroll
        for (int j = 0; j < 8; ++j) s += adjW(node, j) * xS[base + j][c];
        axS[r][c] = s;
    }
    __syncthreads();

    // ---- layer 0 (K=2) + LN + relu -> hT, two-pass (no ov[] buffer) ----
    {
        const int r = t >> 2, cb = (t & 3) * 32;
        const float a0 = axS[r][0], a1 = axS[r][1];
        const float x0 = xS[r][0],  x1 = xS[r][1];
        float s = 0.f, s2 = 0.f;
        #pragma unroll
        for (int i = 0; i < 32; ++i) {
            int o = cb + i;
            float2 wl  = *(const float2*)(Wl0 + o * 2);
            float2 wr_ = *(const float2*)(Wr0 + o * 2);
            float v = bl0[o] + a0 * wl.x + a1 * wl.y + x0 * wr_.x + x1 * wr_.y;
            s += v; s2 += v * v;
        }
        s  += __shfl_xor(s, 1, 64);  s2 += __shfl_xor(s2, 1, 64);
        s  += __shfl_xor(s, 2, 64);  s2 += __shfl_xor(s2, 2, 64);
        const float mu   = s * (1.f / 128.f);
        const float var  = s2 * (1.f / 128.f) - mu * mu;
        const float rstd = rsqrtf(var + 1e-5f);
        #pragma unroll
        for (int j = 0; j < 4; ++j) {
            bf16x8 pk;
            #pragma unroll
            for (int i = 0; i < 8; ++i) {
                int o = cb + j * 8 + i;
                float2 wl  = *(const float2*)(Wl0 + o * 2);
                float2 wr_ = *(const float2*)(Wr0 + o * 2);
                float v = bl0[o] + a0 * wl.x + a1 * wl.y + x0 * wr_.x + x1 * wr_.y;
                v = (v - mu) * rstd * lng[o] + lnb[o];
                pk[i] = (short)f2bf(fmaxf(v, 0.f));
            }
            *(bf16x8*)&hT[r][cb + j * 8] = pk;
        }
    }
    __syncthreads();   // hT(h0) ready; Wl(lay1) staged (vmcnt drained by barrier)

    // ---- layers 1,2 ----
    #pragma unroll 1
    for (int lay = 0; lay < 2; ++lay) {
        // load h A-frags from hT
        bf16x8 hA[2][4];
        #pragma unroll
        for (int mt = 0; mt < 2; ++mt)
            #pragma unroll
            for (int ks = 0; ks < 4; ++ks)
                hA[mt][ks] = *(const bf16x8*)&hT[wr * 32 + 16 * mt + lc][ks * 32 + kgrp];

        f32x4 acc[2][4];
        #pragma unroll
        for (int mt = 0; mt < 2; ++mt)
            #pragma unroll
            for (int nt = 0; nt < 4; ++nt) acc[mt][nt] = (f32x4){0.f, 0.f, 0.f, 0.f};

        // pass 1: Y1 = h @ Wl^T (wlds = Wl(lay))
        #pragma unroll
        for (int ks = 0; ks < 4; ++ks) {
            const int kb = ks * 32 + kgrp;
            #pragma unroll
            for (int nt = 0; nt < 4; ++nt) {
                bf16x8 b = rdW(wlds, wc * 64 + nt * 16 + lc, kb);
                acc[0][nt] = __builtin_amdgcn_mfma_f32_16x16x32_bf16(hA[0][ks], b, acc[0][nt], 0, 0, 0);
                acc[1][nt] = __builtin_amdgcn_mfma_f32_16x16x32_bf16(hA[1][ks], b, acc[1][nt], 0, 0, 0);
            }
        }

        // A-apply in C-frag regs (verified)
        #pragma unroll
        for (int mt = 0; mt < 2; ++mt)
            #pragma unroll
            for (int nt = 0; nt < 4; ++nt) {
                float own[4], oth[4];
                #pragma unroll
                for (int q = 0; q < 4; ++q) {
                    own[q] = acc[mt][nt][q];
                    oth[q] = __shfl_xor(own[q], 16, 64);
                }
                float yL[4], yH[4];
                #pragma unroll
                for (int q = 0; q < 4; ++q) {
                    yL[q] = half ? oth[q] : own[q];
                    yH[q] = half ? own[q] : oth[q];
                }
                float S = yL[0]+yL[1]+yL[2]+yL[3]+yH[0]+yH[1]+yH[2]+yH[3];
                float o0, o1, o2, o3;
                if (!half) {
                    o0 = (S - yL[0] - yH[1] - yH[2] - yH[3]) * 0.25f;
                    o1 = (S - yL[1] - yH[2] - yH[3]) * 0.2f;
                    o2 = (S - yL[2] - yH[3]) * (1.f/6.f);
                    o3 = (S - yL[3]) * (1.f/7.f);
                } else {
                    o0 = (S - yH[0]) * (1.f/7.f);
                    o1 = (S - yH[1] - yL[0]) * (1.f/6.f);
                    o2 = (S - yH[2] - yL[0] - yL[1]) * 0.2f;
                    o3 = (S - yH[3] - yL[0] - yL[1] - yL[2]) * 0.25f;
                }
                acc[mt][nt][0] = o0; acc[mt][nt][1] = o1;
                acc[mt][nt][2] = o2; acc[mt][nt][3] = o3;
            }
        __syncthreads();                 // pass-1 wlds reads done

        // stage Wr(lay)
        stage_w(wbf + 32768 + lay * 16384, wlds, t);
        __syncthreads();                 // Wr ready (barrier drains vmcnt)

        // pass 2: acc += h @ Wr^T
        #pragma unroll
        for (int ks = 0; ks < 4; ++ks) {
            const int kb = ks * 32 + kgrp;
            #pragma unroll
            for (int nt = 0; nt < 4; ++nt) {
                bf16x8 b = rdW(wlds, wc * 64 + nt * 16 + lc, kb);
                acc[0][nt] = __builtin_amdgcn_mfma_f32_16x16x32_bf16(hA[0][ks], b, acc[0][nt], 0, 0, 0);
                acc[1][nt] = __builtin_amdgcn_mfma_f32_16x16x32_bf16(hA[1][ks], b, acc[1][nt], 0, 0, 0);
            }
        }

        // bias + LN stats
        float bias[4];
        #pragma unroll
        for (int nt = 0; nt < 4; ++nt) bias[nt] = bl12[lay * 128 + wc * 64 + nt * 16 + lc];
        float rs[2][4], rq[2][4];
        #pragma unroll
        for (int mt = 0; mt < 2; ++mt) {
            #pragma unroll
            for (int q = 0; q < 4; ++q) { rs[mt][q] = 0.f; rq[mt][q] = 0.f; }
            #pragma unroll
            for (int nt = 0; nt < 4; ++nt)
                #pragma unroll
                for (int q = 0; q < 4; ++q) {
                    float v = acc[mt][nt][q] + bias[nt];
                    acc[mt][nt][q] = v;
                    rs[mt][q] += v; rq[mt][q] += v * v;
                }
            #pragma unroll
            for (int q = 0; q < 4; ++q)
                #pragma unroll
                for (int m = 1; m < 16; m <<= 1) {
                    rs[mt][q] += __shfl_xor(rs[mt][q], m, 64);
                    rq[mt][q] += __shfl_xor(rq[mt][q], m, 64);
                }
        }
        if (lc == 0) {
            #pragma unroll
            for (int mt = 0; mt < 2; ++mt)
                #pragma unroll
                for (int q = 0; q < 4; ++q) {
                    int row = wr * 32 + mt * 16 + li * 4 + q;
                    statS[row][wc * 2]     = rs[mt][q];
                    statS[row][wc * 2 + 1] = rq[mt][q];
                }
        }
        __syncthreads();                 // statS ready; pass-2 wlds reads done

        // stage Wl(lay+1) overlapped with epilogue
        if (lay == 0) stage_w(wbf + 16384, wlds, t);

        // epilogue: LN + relu + residual RMW -> hT (hT stays h master)
        const float* lg = lng + (lay + 1) * 128;
        const float* lb = lnb + (lay + 1) * 128;
        float gam[4], bet[4];
        #pragma unroll
        for (int nt = 0; nt < 4; ++nt) {
            int col = wc * 64 + nt * 16 + lc;
            gam[nt] = lg[col]; bet[nt] = lb[col];
        }
        #pragma unroll
        for (int mt = 0; mt < 2; ++mt)
            #pragma unroll
            for (int q = 0; q < 4; ++q) {
                int row = wr * 32 + mt * 16 + li * 4 + q;
                float4 st = *(const float4*)&statS[row][0];
                float sum = st.x + st.z, sq = st.y + st.w;
                float mu   = sum * (1.f / 128.f);
                float var  = sq * (1.f / 128.f) - mu * mu;
                float rstd = rsqrtf(var + 1e-5f);
                #pragma unroll
                for (int nt = 0; nt < 4; ++nt) {
                    int col = wc * 64 + nt * 16 + lc;
                    float v = (acc[mt][nt][q] - mu) * rstd * gam[nt] + bet[nt];
                    float hn = bf2f(hT[row][col]) + fmaxf(v, 0.f);
                    hT[row][col] = f2bf(hn);
                }
            }
        __syncthreads();                 // h(lay) complete before next hA load
    }

    // ---- node mean -> patch features ----
    {
        const int gi = t >> 5, c0 = t & 31;
        #pragma unroll
        for (int k = 0; k < 4; ++k) {
            int c = c0 + 32 * k;
            float s = 0.f;
            #pragma unroll
            for (int j = 0; j < 8; ++j) s += bf2f(hT[gi * 8 + j][c]);
            pf[(size_t)(g0 + gi) * 128 + c] = s * 0.125f;
        }
    }
}

// =====================================================================
// K2: xg1 = pf(63488,128) @ wih1^T(384,128) + bih1 -> bf16.  MFMA, no LDS.
// =====================================================================
__global__ __launch_bounds__(256) void k2_xg(
    const float* __restrict__ src, const unsigned short* __restrict__ wB,
    const float* __restrict__ bias, unsigned short* __restrict__ out)
{
    const int t = threadIdx.x, w = t >> 6, l = t & 63;
    const int lc = l & 15, li = l >> 4;
    const int m0 = blockIdx.x * 64 + w * 16;

    bf16x8 aA[4];
    #pragma unroll
    for (int ks = 0; ks < 4; ++ks) {
        const float* p = src + (size_t)(m0 + lc) * 128 + ks * 32 + li * 8;
        float4 f0 = *(const float4*)p;
        float4 f1 = *(const float4*)(p + 4);
        bf16x8 v;
        v[0] = (short)f2bf(f0.x); v[1] = (short)f2bf(f0.y);
        v[2] = (short)f2bf(f0.z); v[3] = (short)f2bf(f0.w);
        v[4] = (short)f2bf(f1.x); v[5] = (short)f2bf(f1.y);
        v[6] = (short)f2bf(f1.z); v[7] = (short)f2bf(f1.w);
        aA[ks] = v;
    }
    #pragma unroll 2
    for (int nt = 0; nt < 24; ++nt) {
        f32x4 acc = (f32x4){0.f, 0.f, 0.f, 0.f};
        #pragma unroll
        for (int ks = 0; ks < 4; ++ks) {
            bf16x8 b = *(const bf16x8*)&wB[(size_t)(nt * 16 + lc) * 128 + ks * 32 + li * 8];
            acc = __builtin_amdgcn_mfma_f32_16x16x32_bf16(aA[ks], b, acc, 0, 0, 0);
        }
        float bv = bias[nt * 16 + lc];
        #pragma unroll
        for (int q = 0; q < 4; ++q) {
            int m = m0 + li * 4 + q;
            out[(size_t)m * 384 + nt * 16 + lc] = f2bf(acc[q] + bv);
        }
    }
}

// =====================================================================
// K3: both GRU layers fused, 31 steps in-kernel, weights in registers.
// =====================================================================
__global__ __launch_bounds__(512, 2) void k3_gru(
    const unsigned short* __restrict__ xg, const unsigned short* __restrict__ wbf,
    const float* __restrict__ bih, const float* __restrict__ bhh,
    float* __restrict__ gbuf)
{
    __shared__ unsigned short h1S[16][136];
    __shared__ unsigned short h2S[16][136];

    const int t = threadIdx.x, w = t >> 6, l = t & 63;
    const int lc = l & 15, li = l >> 4;
    const int col = w * 16 + lc;          // 0..127
    const int kgrp = li * 8;
    const int b0 = blockIdx.x * 8;
    const bool act = (li < 2);

    for (int i = t; i < 16 * 136; i += 512) {
        ((unsigned short*)h1S)[i] = 0;
        ((unsigned short*)h2S)[i] = 0;
    }

    const unsigned short* wih2 = wbf + 114688;
    const unsigned short* whh1 = wbf + 163840;
    const unsigned short* whh2 = wbf + 212992;
    bf16x8 Wh1[3][4], Wi2[3][4], Wh2[3][4];
    #pragma unroll
    for (int g = 0; g < 3; ++g)
        #pragma unroll
        for (int ks = 0; ks < 4; ++ks) {
            size_t off = (size_t)(g * 128 + col) * 128 + ks * 32 + kgrp;
            Wh1[g][ks] = *(const bf16x8*)(whh1 + off);
            Wi2[g][ks] = *(const bf16x8*)(wih2 + off);
            Wh2[g][ks] = *(const bf16x8*)(whh2 + off);
        }
    float bh1[3], bi2[3], bh2[3];
    #pragma unroll
    for (int g = 0; g < 3; ++g) {
        bh1[g] = bhh[g * 128 + col];
        bi2[g] = bih[384 + g * 128 + col];
        bh2[g] = bhh[384 + g * 128 + col];
    }

    float h1r[4] = {0.f, 0.f, 0.f, 0.f};
    float h2r[4] = {0.f, 0.f, 0.f, 0.f};
    float x1[3][4];

    if (act) {
        #pragma unroll
        for (int g = 0; g < 3; ++g)
            #pragma unroll
            for (int q = 0; q < 4; ++q)
                x1[g][q] = bf2f(xg[((size_t)(b0 + li * 4 + q) * 31 + 0) * 384 + g * 128 + col]);
    }
    __syncthreads();

    for (int ts = 0; ts < 31; ++ts) {
        bf16x8 aH[4];
        #pragma unroll
        for (int ks = 0; ks < 4; ++ks) aH[ks] = *(const bf16x8*)&h1S[lc][ks * 32 + kgrp];
        f32x4 acc[3];
        #pragma unroll
        for (int g = 0; g < 3; ++g) {
            acc[g] = (f32x4){0.f, 0.f, 0.f, 0.f};
            #pragma unroll
            for (int ks = 0; ks < 4; ++ks)
                acc[g] = __builtin_amdgcn_mfma_f32_16x16x32_bf16(aH[ks], Wh1[g][ks], acc[g], 0, 0, 0);
        }
        float xn[3][4];
        if (act && ts < 30) {
            #pragma unroll
            for (int g = 0; g < 3; ++g)
                #pragma unroll
                for (int q = 0; q < 4; ++q)
                    xn[g][q] = bf2f(xg[((size_t)(b0 + li * 4 + q) * 31 + ts + 1) * 384 + g * 128 + col]);
        }
        if (act) {
            #pragma unroll
            for (int q = 0; q < 4; ++q) {
                float r  = sigm(x1[0][q] + acc[0][q] + bh1[0]);
                float z  = sigm(x1[1][q] + acc[1][q] + bh1[1]);
                float nn = tanh_(x1[2][q] + r * (acc[2][q] + bh1[2]));
                h1r[q] = (1.f - z) * nn + z * h1r[q];
            }
        }
        __syncthreads();
        if (act) {
            #pragma unroll
            for (int q = 0; q < 4; ++q) h1S[li * 4 + q][col] = f2bf(h1r[q]);
        }
        __syncthreads();

        bf16x8 aH1n[4], aH2[4];
        #pragma unroll
        for (int ks = 0; ks < 4; ++ks) {
            aH1n[ks] = *(const bf16x8*)&h1S[lc][ks * 32 + kgrp];
            aH2[ks]  = *(const bf16x8*)&h2S[lc][ks * 32 + kgrp];
        }
        f32x4 ax2[3], ah2[3];
        #pragma unroll
        for (int g = 0; g < 3; ++g) {
            ax2[g] = (f32x4){0.f, 0.f, 0.f, 0.f};
            ah2[g] = (f32x4){0.f, 0.f, 0.f, 0.f};
            #pragma unroll
            for (int ks = 0; ks < 4; ++ks) {
                ax2[g] = __builtin_amdgcn_mfma_f32_16x16x32_bf16(aH1n[ks], Wi2[g][ks], ax2[g], 0, 0, 0);
                ah2[g] = __builtin_amdgcn_mfma_f32_16x16x32_bf16(aH2[ks],  Wh2[g][ks], ah2[g], 0, 0, 0);
            }
        }
        if (act) {
            #pragma unroll
            for (int q = 0; q < 4; ++q) {
                float xr = ax2[0][q] + bi2[0];
                float xz = ax2[1][q] + bi2[1];
                float xn2 = ax2[2][q] + bi2[2];
                float r  = sigm(xr + ah2[0][q] + bh2[0]);
                float z  = sigm(xz + ah2[1][q] + bh2[1]);
                float nn = tanh_(xn2 + r * (ah2[2][q] + bh2[2]));
                h2r[q] = (1.f - z) * nn + z * h2r[q];
            }
        }
        __syncthreads();
        if (act) {
            #pragma unroll
            for (int q = 0; q < 4; ++q) h2S[li * 4 + q][col] = f2bf(h2r[q]);
        }
        __syncthreads();

        #pragma unroll
        for (int g = 0; g < 3; ++g)
            #pragma unroll
            for (int q = 0; q < 4; ++q) x1[g][q] = xn[g][q];
    }

    if (act) {
        #pragma unroll
        for (int q = 0; q < 4; ++q)
            gbuf[(size_t)(b0 + li * 4 + q) * 128 + col] = h2r[q];
    }
}

// =====================================================================
// K4: logits = g(2048,128) @ etf(128,8)
// =====================================================================
__global__ __launch_bounds__(256) void k4_logits(
    const float* __restrict__ g, const float* __restrict__ etf, float* __restrict__ logits)
{
    const int idx = blockIdx.x * 256 + threadIdx.x;
    const int b = idx >> 3, c = idx & 7;
    float s = 0.f;
    #pragma unroll 8
    for (int f = 0; f < 128; ++f) s += g[(size_t)b * 128 + f] * etf[f * 8 + c];
    logits[idx] = s;
}

// =====================================================================
extern "C" void kernel_launch(void* const* d_in, const int* in_sizes, int n_in,
                              void* d_out, int out_size, void* d_ws, size_t ws_size,
                              hipStream_t stream) {
    const float* iq   = (const float*)d_in[0];
    const float* Wl0  = (const float*)d_in[1];
    const float* bl0  = (const float*)d_in[2];
    const float* Wr0  = (const float*)d_in[3];
    const float* Wl12 = (const float*)d_in[4];
    const float* bl12 = (const float*)d_in[5];
    const float* Wr12 = (const float*)d_in[6];
    const float* lng  = (const float*)d_in[7];
    const float* lnb  = (const float*)d_in[8];
    const float* wih  = (const float*)d_in[9];
    const float* whh  = (const float*)d_in[10];
    const float* bih  = (const float*)d_in[11];
    const float* bhh  = (const float*)d_in[12];
    const float* etf  = (const float*)d_in[13];

    float* out    = (float*)d_out;
    float* logits = out;                       // 2048*8
    float* gbuf   = out + 16384;               // 2048*128
    float* pf     = out + 16384 + 262144;      // 63488*128

    // ws: [wbf 262144 u16 = 512KB][xg1 bf16 63488*384 u16 = 48.76MB]
    unsigned short* wbf = (unsigned short*)d_ws;
    unsigned short* xg  = wbf + 262144;

    k0_wconv<<<1024, 256, 0, stream>>>(Wl12, Wr12, wih, whh, wbf);
    k1_sage<<<3968, 512, 0, stream>>>(iq, Wl0, bl0, Wr0, wbf, bl12, lng, lnb, pf);
    k2_xg<<<992, 256, 0, stream>>>(pf, wbf + 65536, bih, xg);
    k3_gru<<<256, 512, 0, stream>>>(xg, wbf, bih, bhh, gbuf);
    k4_logits<<<64, 256, 0, stream>>>(gbuf, etf, logits);
}